// Round 4
// baseline (498.027 us; speedup 1.0000x reference)
//
#include <hip/hip_runtime.h>

typedef __attribute__((ext_vector_type(4))) float f4;
typedef __attribute__((ext_vector_type(4))) float f32x4;
typedef __attribute__((ext_vector_type(8))) short short8;
typedef __attribute__((ext_vector_type(4))) short short4v;

#define S_  4096
#define NB_ 16
#define SLOPE_SCALE 0.838719677419355f

__device__ __forceinline__ float slope_for_head(int h) {
    return exp2f(-(float)(h + 1) * 0.125f) * SLOPE_SCALE;
}

// fp32 -> bf16 round-to-nearest-even
__device__ __forceinline__ short f2bf(float f) {
    unsigned u = __float_as_uint(f);
    u += 0x7FFFu + ((u >> 16) & 1u);
    return (short)(u >> 16);
}
__device__ __forceinline__ float bf2f(short s) {
    return __uint_as_float(((unsigned)(unsigned short)s) << 16);
}

// XOR swizzle for [row][n32] hi/lo LDS arrays (stride 40 shorts): spreads the
// 8-row same-bank-group aliasing to ~2-way (free). n8 is 8-aligned.
__device__ __forceinline__ int NX(int row, int n8) {
    return n8 ^ (((row >> 3) & 3) << 3);
}

// LDS-only barrier: does NOT drain vmcnt, so global stores (vt/kbf) and
// next-stage register prefetches stay in flight across it.
#define LDS_BAR() do {                                        \
    asm volatile("s_waitcnt lgkmcnt(0)" ::: "memory");        \
    __builtin_amdgcn_s_barrier();                             \
    __builtin_amdgcn_sched_barrier(0);                        \
} while (0)

// ---------------------------------------------------------------------------
// Phase 1 (MFMA): per-(bh, j): KVT[e][d] = sum_n v[n][e]*kd[n]*k[n][d]
// 8 stages of 32 rows. Column loads (lane=d/e, wave=8-n chunk; each load is a
// fully-coalesced 256B row) -> hi/lo bf16 convert IN REGISTERS -> write the
// transposed LDS layout the MFMA-read section consumes (read side identical
// to the verified round-3 kernel). 2 LDS-only barriers/stage, 20KB LDS.
// Side outputs: vt (masked V^T bf16, chunk-tiled) straight from registers;
// kbf (bf16 k, row-major) via secondary row-pattern reads (L1 hits).
// ---------------------------------------------------------------------------
template<int USE_KBF>
__global__ __launch_bounds__(256, 4) void phase1_kvblocks(
    const float* __restrict__ k, const float* __restrict__ v,
    const int* __restrict__ mask, float* __restrict__ kvt,
    short* __restrict__ vt, short* __restrict__ kbf)
{
    __shared__ short khi[64][40];    // [d][n32] bf16 hi (NX-swizzled)
    __shared__ short klo[64][40];
    __shared__ short vhi[64][40];    // [e][n32]
    __shared__ short vlo[64][40];
    const int j  = blockIdx.x;       // 0..15
    const int bh = blockIdx.y;       // 0..127
    const int b  = bh >> 6;
    const int h  = bh & 63;
    const int t  = threadIdx.x;
    const int wave = t >> 6, lane = t & 63, quad = lane >> 4, l16 = lane & 15;
    const float slope = slope_for_head(h);

    // er powers for factored kd: kd(n0+jj) = kd(n0) * er^jj
    const float er = __expf(slope);
    float erp[8];
    erp[0] = 1.f;
    #pragma unroll
    for (int jj = 1; jj < 8; ++jj) erp[jj] = erp[jj - 1] * er;

    const f32x4 zf = {0.f, 0.f, 0.f, 0.f};
    f32x4 acc[4];                    // wave owns e-block = wave*16..+15; dt=0..3
    acc[0] = zf; acc[1] = zf; acc[2] = zf; acc[3] = zf;

    const long long tilebase = ((long long)bh * S_ + j * 256) * 64;
    const long long vtbase   = ((long long)(bh * NB_ + j)) * 16384;
    const int mbase = b * S_ + j * 256;

    const int r0   = t >> 4;         // 0..15  (kbf row pattern)
    const int colr = (t & 15) << 2;  // 0..60

    float kc[8], vc[8], kn[8], vn[8];
    float mk[8], mn[8];

    auto LOADC = [&](int ss, float* kcd, float* vcd, float* mm) {
        const long long g = tilebase + (long long)(ss * 32 + wave * 8) * 64 + lane;
        #pragma unroll
        for (int jj = 0; jj < 8; ++jj) {
            kcd[jj] = k[g + jj * 64];
            vcd[jj] = v[g + jj * 64];
            mm[jj]  = (float)mask[mbase + ss * 32 + wave * 8 + jj];  // uniform
        }
    };
    LOADC(0, kc, vc, mk);

    for (int ss = 0; ss < 8; ++ss) {
        // ---- convert in registers ----
        const float kdb = __expf(-slope * (float)(255 - ss * 32 - wave * 8));
        short8 k8h, k8l, v8h, v8l;
        #pragma unroll
        for (int jj = 0; jj < 8; ++jj) {
            float kx = kc[jj] * (kdb * erp[jj]);
            short kh = f2bf(kx);
            k8h[jj] = kh; k8l[jj] = f2bf(kx - bf2f(kh));
            float vx = vc[jj] * mk[jj];
            short vh = f2bf(vx);
            v8h[jj] = vh; v8l[jj] = f2bf(vx - bf2f(vh));
        }
        const int ni = NX(lane, wave * 8);
        *(short8*)&khi[lane][ni] = k8h;
        *(short8*)&klo[lane][ni] = k8l;
        *(short8*)&vhi[lane][ni] = v8h;
        *(short8*)&vlo[lane][ni] = v8l;

        // ---- V^T bf16 straight from registers (tiled layout) ----
        *(short8*)(vt + vtbase + ss * 2048 + lane * 32 + wave * 8) = v8h;

        // ---- kbf via row-pattern (same tile -> L1 hits), bit-identical ----
        if (USE_KBF) {
            long long g0 = tilebase + (long long)(ss * 32 + r0) * 64 + colr;
            f4 kk0 = *(const f4*)(k + g0);
            f4 kk1 = *(const f4*)(k + g0 + 1024);
            short4v b0 = { f2bf(kk0.x), f2bf(kk0.y), f2bf(kk0.z), f2bf(kk0.w) };
            short4v b1 = { f2bf(kk1.x), f2bf(kk1.y), f2bf(kk1.z), f2bf(kk1.w) };
            *(short4v*)(kbf + g0)        = b0;
            *(short4v*)(kbf + g0 + 1024) = b1;
        }

        // ---- prefetch next stage (stays in flight across LDS_BAR) ----
        if (ss < 7) LOADC(ss + 1, kn, vn, mn);

        LDS_BAR();

        // ---- MFMA: one K=32 chunk (read side identical to round 3) ----
        {
            int ar = wave * 16 + l16;
            short8 ahi = *(const short8*)&vhi[ar][NX(ar, quad * 8)];
            short8 alo = *(const short8*)&vlo[ar][NX(ar, quad * 8)];
            #pragma unroll
            for (int dt = 0; dt < 4; ++dt) {
                int br = dt * 16 + l16;
                short8 bhi = *(const short8*)&khi[br][NX(br, quad * 8)];
                short8 blo = *(const short8*)&klo[br][NX(br, quad * 8)];
                acc[dt] = __builtin_amdgcn_mfma_f32_16x16x32_bf16(ahi, bhi, acc[dt], 0, 0, 0);
                acc[dt] = __builtin_amdgcn_mfma_f32_16x16x32_bf16(ahi, blo, acc[dt], 0, 0, 0);
                acc[dt] = __builtin_amdgcn_mfma_f32_16x16x32_bf16(alo, bhi, acc[dt], 0, 0, 0);
            }
        }

        LDS_BAR();

        if (ss < 7) {
            #pragma unroll
            for (int jj = 0; jj < 8; ++jj) {
                kc[jj] = kn[jj]; vc[jj] = vn[jj]; mk[jj] = mn[jj];
            }
        }
    }

    // C frag: e = wave*16 + quad*4 + reg, d = dt*16 + l16
    float* o = kvt + ((long long)(bh * NB_ + j)) * 4096;
    #pragma unroll
    for (int dt = 0; dt < 4; ++dt) {
        #pragma unroll
        for (int r = 0; r < 4; ++r) {
            int e = wave * 16 + quad * 4 + r;
            o[e * 64 + dt * 16 + l16] = acc[dt][r];
        }
    }
}

// ---------------------------------------------------------------------------
// Phase 2: prefix scan over j; optionally emits bf16 copy (kvb) of the
// per-block entering state, in the exact layout phase3's inter A-frags read.
// ---------------------------------------------------------------------------
template<int EMIT>
__global__ __launch_bounds__(256) void phase2_scan(float* __restrict__ kvt,
                                                   short* __restrict__ kvb)
{
    const int g    = blockIdx.x;      // 0..511
    const int bh   = g >> 2;
    const int part = g & 3;
    const int h    = bh & 63;
    const float slope = slope_for_head(h);
    const float bd = __expf(-slope * 256.0f);

    f4* base = (f4*)(kvt + (long long)bh * NB_ * 4096) + part * 256 + threadIdx.x;
    short* kb = kvb + (long long)bh * NB_ * 4096
              + ((long long)(part * 256 + threadIdx.x) << 2);
    f4 vals[NB_];
    #pragma unroll
    for (int jj = 0; jj < NB_; ++jj) vals[jj] = base[jj * 1024];
    f4 st = {0.f, 0.f, 0.f, 0.f};
    #pragma unroll
    for (int jj = 0; jj < NB_; ++jj) {
        base[jj * 1024] = st;         // S_j enters block j
        if (EMIT) {
            short4v sb = { f2bf(st.x), f2bf(st.y), f2bf(st.z), f2bf(st.w) };
            *(short4v*)(kb + (long long)jj * 4096) = sb;
        }
        st = st * bd + vals[jj];
    }
}

// ---------------------------------------------------------------------------
// Phase 3: 4-wave role-balanced structure (unchanged from round 3):
//   - __launch_bounds__(256,3), kf double-buffer, bf16 kvb inter operand,
//     factored causal decay.
// ---------------------------------------------------------------------------
template<int USE_KBF, int USE_KVB>
__global__ __launch_bounds__(256, 3) void phase3_output(
    const float* __restrict__ q, const float* __restrict__ kfp,
    const short* __restrict__ kbf, const float* __restrict__ kvt,
    const short* __restrict__ kvb, const short* __restrict__ vt,
    float* __restrict__ out)
{
    __shared__ short P[4][64 * 56];   // per-wave [64 m][56 stride, 32 n used]
    const int j    = blockIdx.x;      // 0..15
    const int bh   = blockIdx.y;      // 0..127
    const int h    = bh & 63;
    const int tid  = threadIdx.x;
    const int wave = tid >> 6;
    const int lane = tid & 63;
    const int quad = lane >> 4;
    const int l16  = lane & 15;
    const int wrole  = (wave + j) & 3;   // balance causal trip counts across SIMDs
    const float slope = slope_for_head(h);
    const int mwbase = wrole << 6;

    const long long rowbase = (long long)bh * S_ + j * 256 + mwbase;
    const long long kTile = ((long long)bh * S_ + j * 256) * 64;
    const long long vTile = ((long long)(bh * NB_ + j)) * 16384;

    // ---- Q fragments (B-operand layout: B[k=ks*32+quad*8+jj][m=l16]) ----
    short8 qf[4][2];
    #pragma unroll
    for (int mt = 0; mt < 4; ++mt) {
        const float* qp = q + (rowbase + mt * 16 + l16) * 64 + quad * 8;
        #pragma unroll
        for (int ks = 0; ks < 2; ++ks) {
            f4 a = *(const f4*)(qp + ks * 32);
            f4 b = *(const f4*)(qp + ks * 32 + 4);
            short8 f;
            f[0] = f2bf(a.x); f[1] = f2bf(a.y); f[2] = f2bf(a.z); f[3] = f2bf(a.w);
            f[4] = f2bf(b.x); f[5] = f2bf(b.y); f[6] = f2bf(b.z); f[7] = f2bf(b.w);
            qf[mt][ks] = f;
        }
    }

    auto LOADKF = [&](short8 (&dst)[2][2], int nb0) {
        #pragma unroll
        for (int nt = 0; nt < 2; ++nt) {
            const short* kp = kbf + kTile
                + (long long)(nb0 + nt * 16 + l16) * 64 + quad * 8;
            dst[nt][0] = *(const short8*)(kp);
            dst[nt][1] = *(const short8*)(kp + 32);
        }
    };

    short8 kfA[2][2];
    if (USE_KBF) LOADKF(kfA, 0);     // chunk 0; latency hides under inter

    const f32x4 zf = {0.f, 0.f, 0.f, 0.f};
    f32x4 of[4][4];
    #pragma unroll
    for (int et = 0; et < 4; ++et)
        #pragma unroll
        for (int mt = 0; mt < 4; ++mt) of[et][mt] = zf;

    // ---- inter-block: O^T += kvT @ Q^T ----
    if (USE_KVB) {
        const short* kvbp = kvb + ((long long)(bh * NB_ + j) << 12);
        #pragma unroll
        for (int et = 0; et < 4; ++et) {
            #pragma unroll
            for (int ks = 0; ks < 2; ++ks) {
                short8 af = *(const short8*)(kvbp + (et * 16 + l16) * 64
                                             + ks * 32 + quad * 8);
                #pragma unroll
                for (int mt = 0; mt < 4; ++mt)
                    of[et][mt] = __builtin_amdgcn_mfma_f32_16x16x32_bf16(
                        af, qf[mt][ks], of[et][mt], 0, 0, 0);
            }
        }
    } else {
        const float* kvp = kvt + ((long long)(bh * NB_ + j) << 12);
        #pragma unroll
        for (int et = 0; et < 4; ++et) {
            #pragma unroll
            for (int ks = 0; ks < 2; ++ks) {
                const float* p = kvp + (et * 16 + l16) * 64 + ks * 32 + quad * 8;
                f4 a = *(const f4*)(p);
                f4 b = *(const f4*)(p + 4);
                short8 af;
                af[0] = f2bf(a.x); af[1] = f2bf(a.y); af[2] = f2bf(a.z); af[3] = f2bf(a.w);
                af[4] = f2bf(b.x); af[5] = f2bf(b.y); af[6] = f2bf(b.z); af[7] = f2bf(b.w);
                #pragma unroll
                for (int mt = 0; mt < 4; ++mt)
                    of[et][mt] = __builtin_amdgcn_mfma_f32_16x16x32_bf16(
                        af, qf[mt][ks], of[et][mt], 0, 0, 0);
            }
        }
    }
    // scale columns (m) by q_decay[m] = exp(-slope*(m+1))
    #pragma unroll
    for (int mt = 0; mt < 4; ++mt) {
        float qd = __expf(-slope * (float)(mwbase + mt * 16 + l16 + 1));
        #pragma unroll
        for (int et = 0; et < 4; ++et) of[et][mt] *= qd;
    }

    // ---- intra-block, causal, chunks of 32 n ----
    const float er1 = __expf(slope);
    const float er2 = er1 * er1;
    const float er3 = er2 * er1;
    // factored decay: ddb(nt,mt,lane) = W * L * T^mt * Ti^nt
    const float L  = __expf(-slope * (float)(l16 - quad * 4));
    const float T1 = __expf(-slope * 16.f);
    const float Ti = __expf(slope * 16.f);
    const float Tm[4] = {1.f, T1, T1 * T1, T1 * T1 * T1};

    short* Pw = &P[wave][0];                 // index by PHYSICAL wave (privacy)
    const int nchunks = (mwbase >> 5) + 2;   // covers n < mwbase + 64

    for (int c = 0; c < nchunks; ++c) {
        const int nbase = c << 5;
        const bool havenext = (c + 1 < nchunks);

        // V^T A-fragments — issue early, used after the P phase
        short8 va[4];
        #pragma unroll
        for (int et = 0; et < 4; ++et)
            va[et] = *(const short8*)(vt + vTile + c * 2048
                                      + (et * 16 + l16) * 32 + quad * 8);

        // prefetch next chunk's K fragments (completes under P/PV below)
        short8 kfB[2][2];
        if (USE_KBF && havenext) LOADKF(kfB, nbase + 32);

        if (!USE_KBF) {
            #pragma unroll
            for (int nt = 0; nt < 2; ++nt) {
                const float* kp = kfp + kTile
                    + (long long)(nbase + nt * 16 + l16) * 64 + quad * 8;
                #pragma unroll
                for (int ks = 0; ks < 2; ++ks) {
                    f4 a = *(const f4*)(kp + ks * 32);
                    f4 b = *(const f4*)(kp + ks * 32 + 4);
                    short8 f;
                    f[0] = f2bf(a.x); f[1] = f2bf(a.y); f[2] = f2bf(a.z); f[3] = f2bf(a.w);
                    f[4] = f2bf(b.x); f[5] = f2bf(b.y); f[6] = f2bf(b.z); f[7] = f2bf(b.w);
                    kfA[nt][ks] = f;
                }
            }
        }

        // S^T = K @ Q^T  (C frag: row = n local = quad*4+reg, col = m = l16)
        f32x4 sf[2][4];
        #pragma unroll
        for (int nt = 0; nt < 2; ++nt)
            #pragma unroll
            for (int mt = 0; mt < 4; ++mt) sf[nt][mt] = zf;
        #pragma unroll
        for (int nt = 0; nt < 2; ++nt)
            #pragma unroll
            for (int ks = 0; ks < 2; ++ks)
                #pragma unroll
                for (int mt = 0; mt < 4; ++mt)
                    sf[nt][mt] = __builtin_amdgcn_mfma_f32_16x16x32_bf16(
                        kfA[nt][ks], qf[mt][ks], sf[nt][mt], 0, 0, 0);

        // apply causal decay (factored), cast bf16, store to per-wave P
        const float WL = __expf(-slope * (float)(mwbase - nbase)) * L;
        #pragma unroll
        for (int nt = 0; nt < 2; ++nt) {
            #pragma unroll
            for (int mt = 0; mt < 4; ++mt) {
                int n0 = nbase + nt * 16 + quad * 4;       // n at reg 0
                int m  = mwbase + mt * 16 + l16;
                float ddb = WL * Tm[mt];
                if (nt) ddb *= Ti;
                f32x4 s = sf[nt][mt];
                float v0 = (m >= n0)     ? s[0] * ddb       : 0.f;
                float v1 = (m >= n0 + 1) ? s[1] * ddb * er1 : 0.f;
                float v2 = (m >= n0 + 2) ? s[2] * ddb * er2 : 0.f;
                float v3 = (m >= n0 + 3) ? s[3] * ddb * er3 : 0.f;
                short4v pk = {f2bf(v0), f2bf(v1), f2bf(v2), f2bf(v3)};
                *(short4v*)&Pw[(mt * 16 + l16) * 56 + nt * 16 + quad * 4] = pk;
            }
        }
        asm volatile("s_waitcnt lgkmcnt(0)" ::: "memory");

        // P B-fragments (B[k=n=quad*8+jj][m=l16]) — contiguous b128 reads
        short8 pb[4];
        #pragma unroll
        for (int mt = 0; mt < 4; ++mt)
            pb[mt] = *(const short8*)&Pw[(mt * 16 + l16) * 56 + quad * 8];

        #pragma unroll
        for (int et = 0; et < 4; ++et)
            #pragma unroll
            for (int mt = 0; mt < 4; ++mt)
                of[et][mt] = __builtin_amdgcn_mfma_f32_16x16x32_bf16(
                    va[et], pb[mt], of[et][mt], 0, 0, 0);

        if (USE_KBF && havenext) {
            #pragma unroll
            for (int nt = 0; nt < 2; ++nt) {
                kfA[nt][0] = kfB[nt][0];
                kfA[nt][1] = kfB[nt][1];
            }
        }
    }

    // ---- epilogue: O^T frag (row=e, col=m) -> out[m][e], float4 stores ----
    #pragma unroll
    for (int mt = 0; mt < 4; ++mt) {
        float* orow = out + (rowbase + mt * 16 + l16) * 64;
        #pragma unroll
        for (int et = 0; et < 4; ++et) {
            f4 o = {of[et][mt][0], of[et][mt][1], of[et][mt][2], of[et][mt][3]};
            *(f4*)(orow + et * 16 + quad * 4) = o;
        }
    }
}

// ---------------------------------------------------------------------------
extern "C" void kernel_launch(void* const* d_in, const int* in_sizes, int n_in,
                              void* d_out, int out_size, void* d_ws, size_t ws_size,
                              hipStream_t stream) {
    const float* q    = (const float*)d_in[0];
    const float* k    = (const float*)d_in[1];
    const float* v    = (const float*)d_in[2];
    const int*   mask = (const int*)d_in[3];
    float* kvt = (float*)d_ws;                                        // 32 MiB
    short* vt  = (short*)((char*)d_ws + (size_t)33554432);            // 64 MiB
    short* kbf = (short*)((char*)d_ws + (size_t)100663296);           // 64 MiB
    short* kvb = (short*)((char*)d_ws + (size_t)167772160);           // 16 MiB
    float* out = (float*)d_out;

    if (ws_size >= (size_t)184549376) {            // kvt+vt+kbf+kvb
        phase1_kvblocks<1><<<dim3(16, 128), 256, 0, stream>>>(k, v, mask, kvt, vt, kbf);
        phase2_scan<1><<<512, 256, 0, stream>>>(kvt, kvb);
        phase3_output<1, 1><<<dim3(16, 128), 256, 0, stream>>>(q, k, kbf, kvt, kvb, vt, out);
    } else if (ws_size >= (size_t)167772160) {     // kvt+vt+kbf
        phase1_kvblocks<1><<<dim3(16, 128), 256, 0, stream>>>(k, v, mask, kvt, vt, kbf);
        phase2_scan<0><<<512, 256, 0, stream>>>(kvt, kvb);
        phase3_output<1, 0><<<dim3(16, 128), 256, 0, stream>>>(q, k, kbf, kvt, kvb, vt, out);
    } else {                                       // kvt+vt only
        phase1_kvblocks<0><<<dim3(16, 128), 256, 0, stream>>>(k, v, mask, kvt, vt, kbf);
        phase2_scan<0><<<512, 256, 0, stream>>>(kvt, kvb);
        phase3_output<0, 0><<<dim3(16, 128), 256, 0, stream>>>(q, k, kbf, kvt, kvb, vt, out);
    }
}